// Round 8
// baseline (197.497 us; speedup 1.0000x reference)
//
#include <hip/hip_runtime.h>
#include <cstdint>

#define NROWS 16384
#define ARRE ((size_t)NROWS * 128)

typedef short short8 __attribute__((ext_vector_type(8)));
typedef float f32x4  __attribute__((ext_vector_type(4)));
typedef float f32x16 __attribute__((ext_vector_type(16)));

static __device__ __forceinline__ unsigned short f2bf(float f) {
    union { float f; uint32_t u; } v; v.f = f;
    uint32_t r = v.u + 0x7fffu + ((v.u >> 16) & 1u);   // RNE
    return (unsigned short)(r >> 16);
}

static __device__ __forceinline__ uint32_t cvt_pk_bf16(float lo, float hi) {
    uint32_t r;
    asm("v_cvt_pk_bf16_f32 %0, %1, %2" : "=v"(r) : "v"(lo), "v"(hi));
    return r;
}

static __device__ __forceinline__ float v_exp2(float x) {   // 2^x, single instr
    float r;
    asm("v_exp_f32 %0, %1" : "=v"(r) : "v"(x));
    return r;
}

// ---------------------------------------------------------------- weights -> bf16 transposed (+ mask detect)
// wT layout: [0,49152) wqkvT[384][128]; [49152,65536) w1T[128][128]; [65536,81920) w2T
__global__ void k_castw(const float* __restrict__ wqkv, const float* __restrict__ w1,
                        const float* __restrict__ w2, unsigned short* __restrict__ wT,
                        const uint32_t* __restrict__ mask, int* __restrict__ flag)
{
    if (blockIdx.x == 320) {
        if (threadIdx.x == 0) {
            int f = 0;
            for (int i = 0; i < 256; ++i) f |= (mask[i] > 1u) ? 1 : 0;
            *flag = f;   // 1 => byte bool mask, 0 => int32 mask
        }
        return;
    }
    const int e = blockIdx.x * 256 + threadIdx.x;
    if (e < 49152) {
        const int n = e >> 7, k = e & 127;
        wT[e] = f2bf(wqkv[k * 384 + n]);
    } else if (e < 65536) {
        const int i = e - 49152, n = i >> 7, k = i & 127;
        wT[e] = f2bf(w1[k * 128 + n]);
    } else if (e < 81920) {
        const int i = e - 65536, n = i >> 7, k = i & 127;
        wT[e] = f2bf(w2[k * 128 + n]);
    }
}

// ---------------------------------------------------------------- MFMA QKV GEMM (K=128, 64 rows x 128 cols)
// Swapped operands: D col = X row (l15), D row = weight col (l4*4+reg).
// blockIdx.y selects Q/K/V; Q pre-scaled by 0.25*log2(e) (exp2-domain softmax).
template<int NF, int MODE>
__global__ __launch_bounds__(256, 2) void k_mm(const float* __restrict__ Xf,
        const unsigned short* __restrict__ Wt, const float* __restrict__ bias,
        unsigned short* __restrict__ out)
{
    __shared__ char smem[16384 + NF * 4096];
    char* const sX = smem;
    char* const sW = smem + 16384;
    const int t = threadIdx.x;
    const int w = t >> 6, l = t & 63;
    const int l4 = l >> 4, l15 = l & 15;
    const int r0 = blockIdx.x * 64;
    const int c0 = blockIdx.y * (NF * 16);

    #pragma unroll
    for (int i = 0; i < 4; ++i) {
        const int c = t + 256 * i;
        const int row = c >> 4, slot = c & 15;
        const float4* src = (const float4*)(Xf + (size_t)(r0 + row) * 128 + slot * 8);
        float4 f0 = src[0], f1 = src[1];
        uint4 v;
        v.x = cvt_pk_bf16(f0.x, f0.y);
        v.y = cvt_pk_bf16(f0.z, f0.w);
        v.z = cvt_pk_bf16(f1.x, f1.y);
        v.w = cvt_pk_bf16(f1.z, f1.w);
        *(uint4*)(sX + row * 256 + ((slot ^ (row & 15)) << 4)) = v;
    }
    #pragma unroll
    for (int i = 0; i < NF; ++i) {
        const int c = t + 256 * i;
        const int col = c >> 4, slot = c & 15;
        uint4 v = *(const uint4*)(Wt + (size_t)(c0 + col) * 128 + slot * 8);
        *(uint4*)(sW + col * 256 + ((slot ^ (col & 15)) << 4)) = v;
    }
    __syncthreads();

    short8 aF[4];
    #pragma unroll
    for (int kk = 0; kk < 4; ++kk)
        aF[kk] = *(const short8*)(sX + (w * 16 + l15) * 256 + (((kk * 4 + l4) ^ l15) << 4));

    f32x4 acc[NF];
    #pragma unroll
    for (int nf = 0; nf < NF; ++nf) acc[nf] = f32x4{0.f, 0.f, 0.f, 0.f};
    #pragma unroll
    for (int nf = 0; nf < NF; ++nf) {
        #pragma unroll
        for (int kk = 0; kk < 4; ++kk) {
            short8 bF = *(const short8*)(sW + (nf * 16 + l15) * 256 + (((kk * 4 + l4) ^ l15) << 4));
            acc[nf] = __builtin_amdgcn_mfma_f32_16x16x32_bf16(bF, aF[kk], acc[nf], 0, 0, 0);
        }
    }

    // Q scale folds hd^-0.5 * log2(e) so softmax can use exp2 directly
    const float scl = (MODE == 0 && blockIdx.y == 0) ? 0.36067376022224085f : 1.0f;
    const int row = r0 + w * 16 + l15;
    #pragma unroll
    for (int nf = 0; nf < NF; ++nf) {
        const int cb = nf * 16 + l4 * 4;
        float4 bv = *(const float4*)(bias + c0 + cb);
        float v0 = acc[nf][0] + bv.x, v1 = acc[nf][1] + bv.y;
        float v2 = acc[nf][2] + bv.z, v3 = acc[nf][3] + bv.w;
        if (MODE == 1) {
            v0 = fmaxf(v0, 0.f); v1 = fmaxf(v1, 0.f);
            v2 = fmaxf(v2, 0.f); v3 = fmaxf(v3, 0.f);
        }
        v0 *= scl; v1 *= scl; v2 *= scl; v3 *= scl;
        uint2 pk;
        pk.x = cvt_pk_bf16(v0, v1);
        pk.y = cvt_pk_bf16(v2, v3);
        size_t o;
        if (MODE == 0) o = (size_t)blockIdx.y * ARRE + (size_t)row * 128 + cb;
        else           o = (size_t)row * 128 + c0 + cb;
        *(uint2*)(out + o) = pk;
    }
}

// ---------------------------------------------------------------- fused FFN: out = LN2(x1 + relu(x1@W1+b1)@W2 + b2)
__global__ __launch_bounds__(256, 2) void k_ffn(const float* __restrict__ x1,
        const unsigned short* __restrict__ w1t, const float* __restrict__ b1,
        const unsigned short* __restrict__ w2t, const float* __restrict__ b2,
        const float* __restrict__ g2, const float* __restrict__ be2,
        float* __restrict__ out)
{
    __shared__ char smem[49152];
    char* const sX = smem;            // X tile, then h1 tile
    char* const sW = smem + 16384;    // w1T, then w2T
    const int t = threadIdx.x;
    const int w = t >> 6, l = t & 63;
    const int l4 = l >> 4, l15 = l & 15;
    const int r0 = blockIdx.x * 64;

    #pragma unroll
    for (int i = 0; i < 4; ++i) {
        const int c = t + 256 * i;
        const int row = c >> 4, slot = c & 15;
        const float4* src = (const float4*)(x1 + (size_t)(r0 + row) * 128 + slot * 8);
        float4 f0 = src[0], f1 = src[1];
        uint4 v;
        v.x = cvt_pk_bf16(f0.x, f0.y);
        v.y = cvt_pk_bf16(f0.z, f0.w);
        v.z = cvt_pk_bf16(f1.x, f1.y);
        v.w = cvt_pk_bf16(f1.z, f1.w);
        *(uint4*)(sX + row * 256 + ((slot ^ (row & 15)) << 4)) = v;
    }
    #pragma unroll
    for (int i = 0; i < 8; ++i) {
        const int c = t + 256 * i;
        const int col = c >> 4, slot = c & 15;
        uint4 v = *(const uint4*)(w1t + (size_t)col * 128 + slot * 8);
        *(uint4*)(sW + col * 256 + ((slot ^ (col & 15)) << 4)) = v;
    }
    __syncthreads();

    short8 aF[4];
    #pragma unroll
    for (int kk = 0; kk < 4; ++kk)
        aF[kk] = *(const short8*)(sX + (w * 16 + l15) * 256 + (((kk * 4 + l4) ^ l15) << 4));

    f32x4 acc[8];
    #pragma unroll
    for (int nf = 0; nf < 8; ++nf) acc[nf] = f32x4{0.f, 0.f, 0.f, 0.f};
    #pragma unroll
    for (int nf = 0; nf < 8; ++nf) {
        #pragma unroll
        for (int kk = 0; kk < 4; ++kk) {
            short8 bF = *(const short8*)(sW + (nf * 16 + l15) * 256 + (((kk * 4 + l4) ^ l15) << 4));
            acc[nf] = __builtin_amdgcn_mfma_f32_16x16x32_bf16(bF, aF[kk], acc[nf], 0, 0, 0);
        }
    }
    __syncthreads();   // all waves done reading sX/sW

    // h1 = relu(acc + b1) -> bf16 -> sX (same swizzled layout); row = w*16+l15
    {
        const int hrow = w * 16 + l15;
        #pragma unroll
        for (int nf = 0; nf < 8; ++nf) {
            const int cb = nf * 16 + l4 * 4;
            float4 bv = *(const float4*)(b1 + cb);
            float v0 = fmaxf(acc[nf][0] + bv.x, 0.f);
            float v1 = fmaxf(acc[nf][1] + bv.y, 0.f);
            float v2 = fmaxf(acc[nf][2] + bv.z, 0.f);
            float v3 = fmaxf(acc[nf][3] + bv.w, 0.f);
            uint2 pk;
            pk.x = cvt_pk_bf16(v0, v1);
            pk.y = cvt_pk_bf16(v2, v3);
            const int slot = (2 * nf) + (l4 >> 1);
            const int off  = (l4 & 1) * 8;
            *(uint2*)(sX + hrow * 256 + ((slot ^ (hrow & 15)) << 4) + off) = pk;
        }
    }
    // stage w2T into sW
    #pragma unroll
    for (int i = 0; i < 8; ++i) {
        const int c = t + 256 * i;
        const int col = c >> 4, slot = c & 15;
        uint4 v = *(const uint4*)(w2t + (size_t)col * 128 + slot * 8);
        *(uint4*)(sW + col * 256 + ((slot ^ (col & 15)) << 4)) = v;
    }
    __syncthreads();

    short8 aG[4];
    #pragma unroll
    for (int kk = 0; kk < 4; ++kk)
        aG[kk] = *(const short8*)(sX + (w * 16 + l15) * 256 + (((kk * 4 + l4) ^ l15) << 4));

    f32x4 acc2[8];
    #pragma unroll
    for (int nf = 0; nf < 8; ++nf) acc2[nf] = f32x4{0.f, 0.f, 0.f, 0.f};
    #pragma unroll
    for (int nf = 0; nf < 8; ++nf) {
        #pragma unroll
        for (int kk = 0; kk < 4; ++kk) {
            short8 bF = *(const short8*)(sW + (nf * 16 + l15) * 256 + (((kk * 4 + l4) ^ l15) << 4));
            acc2[nf] = __builtin_amdgcn_mfma_f32_16x16x32_bf16(bF, aG[kk], acc2[nf], 0, 0, 0);
        }
    }

    // epilogue: y = acc2 + b2 + x1 ; LN2 ; out (fp32)
    const int row = r0 + w * 16 + l15;
    float y[8][4];
    float s = 0.f;
    #pragma unroll
    for (int nf = 0; nf < 8; ++nf) {
        const int cb = nf * 16 + l4 * 4;
        float4 bv = *(const float4*)(b2 + cb);
        float4 xv = *(const float4*)(x1 + (size_t)row * 128 + cb);
        y[nf][0] = acc2[nf][0] + bv.x + xv.x;
        y[nf][1] = acc2[nf][1] + bv.y + xv.y;
        y[nf][2] = acc2[nf][2] + bv.z + xv.z;
        y[nf][3] = acc2[nf][3] + bv.w + xv.w;
        s += y[nf][0] + y[nf][1] + y[nf][2] + y[nf][3];
    }
    s += __shfl_xor(s, 16); s += __shfl_xor(s, 32);
    const float mu = s * (1.f / 128.f);
    float vv = 0.f;
    #pragma unroll
    for (int nf = 0; nf < 8; ++nf) {
        #pragma unroll
        for (int reg = 0; reg < 4; ++reg) { float d = y[nf][reg] - mu; vv += d * d; }
    }
    vv += __shfl_xor(vv, 16); vv += __shfl_xor(vv, 32);
    const float rs = rsqrtf(vv * (1.f / 128.f) + 1e-5f);
    #pragma unroll
    for (int nf = 0; nf < 8; ++nf) {
        const int cb = nf * 16 + l4 * 4;
        float4 gv = *(const float4*)(g2 + cb);
        float4 ev = *(const float4*)(be2 + cb);
        float4 o;
        o.x = (y[nf][0] - mu) * rs * gv.x + ev.x;
        o.y = (y[nf][1] - mu) * rs * gv.y + ev.y;
        o.z = (y[nf][2] - mu) * rs * gv.z + ev.z;
        o.w = (y[nf][3] - mu) * rs * gv.w + ev.w;
        *(float4*)(out + (size_t)row * 128 + cb) = o;
    }
}

// ---------------------------------------------------------------- MFMA flash attention + fused LN1
// 512 threads = 8 waves, wave = head. XCD-swizzled 1D grid (each XCD owns 2 batches).
// K tile: 288B row stride (row-rotated banks). V tile: transposed per head [d][key],
// 80B rows -> PV B-fragment is one aligned ds_read_b128. Softmax in exp2 domain.
//
// LDS map: sK [0,9216) ; sVT [9216,19584) 8 x 1296B ; sP [19584,40064) 8 x 2560B ;
//          sM [40064,40192) ; sS [40192,41216). Epilogue sC fp32[32][132] overlays smem.
__global__ __launch_bounds__(512, 2) void k_attn(
        const unsigned short* __restrict__ qb,
        const unsigned short* __restrict__ kb,
        const unsigned short* __restrict__ vbp,
        const void* __restrict__ maskp, const int* __restrict__ flag,
        const float* __restrict__ x, const float* __restrict__ g1,
        const float* __restrict__ be1, float* __restrict__ x1)
{
    __shared__ alignas(16) char smem[41216];
    char*          const sK  = smem;
    char*          const sVT = smem + 9216;
    char*          const sP  = smem + 19584;
    unsigned char* const sM  = (unsigned char*)(smem + 40064);
    float*         const sS  = (float*)(smem + 40192);

    const int t  = threadIdx.x;
    const int w  = t >> 6;        // head
    const int l  = t & 63;
    const int bid = blockIdx.x;
    const int b  = ((bid & 7) << 1) | ((bid >> 3) >> 5);   // XCD-local batches
    const int q0 = ((bid >> 3) & 31) * 32;
    const int q   = l & 31;
    const int hi  = l >> 5;
    const int l4  = l >> 4;
    const int l15 = l & 15;
    const int bytemask = *flag;

    short8 qf;
    {
        const size_t qrow = (size_t)(b * 1024 + q0 + q) * 128;
        qf = *(const short8*)(qb + qrow + w * 16 + hi * 8);
    }
    float m = -INFINITY, ls = 0.f;
    f32x4 ac0 = {0,0,0,0}, ac1 = {0,0,0,0};
    const f32x16 z16 = {};
    float* const sSw = sS + w * 32;
    char*  const Pw  = sP + w * 2560;

    const uint8_t* m8  = (const uint8_t*)maskp;
    const int*     m32 = (const int*)maskp;

    for (int kt = 0; kt < 32; ++kt) {
        const int k0 = kt * 32;
        __syncthreads();
        // ---- stage K (288B rows, slot-XOR) and V^T (per head [16 d][80B]) ----
        {
            const int row = t >> 4, slot = t & 15;
            const size_t src = (size_t)(b * 1024 + k0 + row) * 128 + slot * 8;
            uint4 kv = *(const uint4*)(kb + src);
            *(uint4*)(sK + row * 288 + ((slot ^ (row & 15)) << 4)) = kv;
            uint4 vv = *(const uint4*)(vbp + src);
            char* vt = sVT + (slot >> 1) * 1296 + (slot & 1) * 640 + row * 2;
            const uint32_t w0 = vv.x, w1 = vv.y, w2 = vv.z, w3 = vv.w;
            *(unsigned short*)(vt + 0 * 80) = (unsigned short)(w0);
            *(unsigned short*)(vt + 1 * 80) = (unsigned short)(w0 >> 16);
            *(unsigned short*)(vt + 2 * 80) = (unsigned short)(w1);
            *(unsigned short*)(vt + 3 * 80) = (unsigned short)(w1 >> 16);
            *(unsigned short*)(vt + 4 * 80) = (unsigned short)(w2);
            *(unsigned short*)(vt + 5 * 80) = (unsigned short)(w2 >> 16);
            *(unsigned short*)(vt + 6 * 80) = (unsigned short)(w3);
            *(unsigned short*)(vt + 7 * 80) = (unsigned short)(w3 >> 16);
        }
        // ---- stage mask keep-bits: [32 q] x 32 keys ----
        if (t < 128) {
            const int mq = t >> 2, g = t & 3;
            const size_t moff = ((size_t)b << 20) + (size_t)(q0 + mq) * 1024
                              + (size_t)(k0 + g * 8);
            unsigned int bits = 0;
            if (bytemask) {
                uint64_t v = *(const uint64_t*)(m8 + moff);
                #pragma unroll
                for (int j = 0; j < 8; ++j)
                    bits |= ((((v >> (8 * j)) & 0xffull) == 0ull) ? 1u : 0u) << j;
            } else {
                const int4* p = (const int4*)(m32 + moff);
                int4 va = p[0], vc = p[1];
                bits = (va.x==0?1u:0u) | (va.y==0?2u:0u) | (va.z==0?4u:0u) | (va.w==0?8u:0u)
                     | (vc.x==0?16u:0u) | (vc.y==0?32u:0u) | (vc.z==0?64u:0u) | (vc.w==0?128u:0u);
            }
            sM[mq * 4 + g] = (unsigned char)bits;
        }
        __syncthreads();

        const uint32_t mk = *(const uint32_t*)(sM + q * 4);
        const uint32_t mks = mk >> (4 * hi);

        // ---- QK^T (swapped: A=K, B=Q) ----
        short8 kf = *(const short8*)(sK + q * 288 + ((((w << 1) + hi) ^ (q & 15)) << 4));
        f32x16 sc = __builtin_amdgcn_mfma_f32_32x32x16_bf16(kf, qf, z16, 0, 0, 0);
        float sm = sc[0];
        #pragma unroll
        for (int r = 1; r < 16; ++r) sm = fmaxf(sm, sc[r]);
        sm = fmaxf(sm, __shfl_xor(sm, 32));
        if (__any(sm > m + 8.f)) {             // defer-max (THR=8, log2 units)
            float nm = fmaxf(m, sm);
            float s  = v_exp2(m - nm);
            m = nm; ls *= s;
            sSw[q] = s;
            float4 s0v = *(float4*)&sSw[l4 * 4];
            float4 s1v = *(float4*)&sSw[l4 * 4 + 16];
            ac0[0] *= s0v.x; ac0[1] *= s0v.y; ac0[2] *= s0v.z; ac0[3] *= s0v.w;
            ac1[0] *= s1v.x; ac1[1] *= s1v.y; ac1[2] *= s1v.z; ac1[3] *= s1v.w;
        }
        float p[16]; float lsum = 0.f;
        #pragma unroll
        for (int r = 0; r < 16; ++r) {
            const int c = (r & 3) + 8 * (r >> 2);       // key = c + 4*hi
            float pv = v_exp2(sc[r] - m);
            pv = ((mks >> c) & 1u) ? pv : 0.f;          // multiplicative mask
            lsum += pv; p[r] = pv;
        }
        ls += lsum;
        #pragma unroll
        for (int g = 0; g < 4; ++g) {
            uint2 pk;
            pk.x = cvt_pk_bf16(p[4*g+0], p[4*g+1]);
            pk.y = cvt_pk_bf16(p[4*g+2], p[4*g+3]);
            *(uint2*)(Pw + q * 80 + (8 * g + 4 * hi) * 2) = pk;
        }
        short8 pa0 = *(const short8*)(Pw + l15 * 80 + l4 * 16);
        short8 pa1 = *(const short8*)(Pw + (l15 + 16) * 80 + l4 * 16);
        short8 vf  = *(const short8*)(sVT + w * 1296 + l15 * 80 + l4 * 16);
        ac0 = __builtin_amdgcn_mfma_f32_16x16x32_bf16(pa0, vf, ac0, 0, 0, 0);
        ac1 = __builtin_amdgcn_mfma_f32_16x16x32_bf16(pa1, vf, ac1, 0, 0, 0);
    }

    __syncthreads();
    // ---- epilogue: normalize, ctx -> LDS fp32 [32][132] ----
    float* const sC = (float*)smem;
    {
        float lt  = ls + __shfl_xor(ls, 32);
        float inv = 1.f / lt;
        sSw[q] = inv;
        float4 i0 = *(float4*)&sSw[l4 * 4];
        float4 i1 = *(float4*)&sSw[l4 * 4 + 16];
        const int cc = w * 16 + l15;
        sC[(l4 * 4 + 0) * 132 + cc]  = ac0[0] * i0.x;
        sC[(l4 * 4 + 1) * 132 + cc]  = ac0[1] * i0.y;
        sC[(l4 * 4 + 2) * 132 + cc]  = ac0[2] * i0.z;
        sC[(l4 * 4 + 3) * 132 + cc]  = ac0[3] * i0.w;
        sC[(l4 * 4 + 16) * 132 + cc] = ac1[0] * i1.x;
        sC[(l4 * 4 + 17) * 132 + cc] = ac1[1] * i1.y;
        sC[(l4 * 4 + 18) * 132 + cc] = ac1[2] * i1.z;
        sC[(l4 * 4 + 19) * 132 + cc] = ac1[3] * i1.w;
    }
    __syncthreads();

    // ---- fused LN1: x1 = LN(x + ctx); 16 lanes/row, 8 cols/lane ----
    {
        const int row = t >> 4;
        const int c0  = (t & 15) * 8;
        const size_t grow = (size_t)(b * 1024 + q0 + row);
        const float4* xp = (const float4*)(x + grow * 128 + c0);
        const float4* cp = (const float4*)(sC + row * 132 + c0);
        float y[8];
        float s = 0.f;
        #pragma unroll
        for (int j = 0; j < 2; ++j) {
            float4 xv = xp[j], cv = cp[j];
            y[4*j+0] = xv.x + cv.x; y[4*j+1] = xv.y + cv.y;
            y[4*j+2] = xv.z + cv.z; y[4*j+3] = xv.w + cv.w;
            s += y[4*j+0] + y[4*j+1] + y[4*j+2] + y[4*j+3];
        }
        s += __shfl_xor(s, 1); s += __shfl_xor(s, 2);
        s += __shfl_xor(s, 4); s += __shfl_xor(s, 8);
        const float mu = s * (1.f / 128.f);
        float vv = 0.f;
        #pragma unroll
        for (int e = 0; e < 8; ++e) { float d = y[e] - mu; vv += d * d; }
        vv += __shfl_xor(vv, 1); vv += __shfl_xor(vv, 2);
        vv += __shfl_xor(vv, 4); vv += __shfl_xor(vv, 8);
        const float rs = rsqrtf(vv * (1.f / 128.f) + 1e-5f);
        #pragma unroll
        for (int j = 0; j < 2; ++j) {
            float4 gv = *(const float4*)(g1 + c0 + 4 * j);
            float4 bv = *(const float4*)(be1 + c0 + 4 * j);
            float4 o;
            o.x = (y[4*j+0] - mu) * rs * gv.x + bv.x;
            o.y = (y[4*j+1] - mu) * rs * gv.y + bv.y;
            o.z = (y[4*j+2] - mu) * rs * gv.z + bv.z;
            o.w = (y[4*j+3] - mu) * rs * gv.w + bv.w;
            *(float4*)(x1 + grow * 128 + c0 + 4 * j) = o;
        }
    }
}

// ---------------------------------------------------------------- launch
extern "C" void kernel_launch(void* const* d_in, const int* in_sizes, int n_in,
                              void* d_out, int out_size, void* d_ws, size_t ws_size,
                              hipStream_t stream)
{
    const float* x    = (const float*)d_in[0];
    const void*  mask = d_in[1];
    const float* wqkv = (const float*)d_in[2];
    const float* bqkv = (const float*)d_in[3];
    const float* w1   = (const float*)d_in[4];
    const float* b1   = (const float*)d_in[5];
    const float* w2   = (const float*)d_in[6];
    const float* b2   = (const float*)d_in[7];
    const float* g1   = (const float*)d_in[8];
    const float* be1  = (const float*)d_in[9];
    const float* g2   = (const float*)d_in[10];
    const float* be2  = (const float*)d_in[11];
    float* out = (float*)d_out;

    char* base = (char*)d_ws;
    int* flag = (int*)base;
    unsigned short* qb  = (unsigned short*)(base + 256);                   // 4MB
    unsigned short* kb  = qb + ARRE;                                       // 4MB
    unsigned short* vb  = kb + ARRE;                                       // 4MB
    float* x1           = (float*)(base + 256 + (size_t)12 * 1024 * 1024); // 8MB
    unsigned short* wT  = (unsigned short*)(base + 256 + (size_t)20 * 1024 * 1024); // 160KB

    k_castw<<<321, 256, 0, stream>>>(wqkv, w1, w2, wT, (const uint32_t*)mask, flag);
    k_mm<8, 0><<<dim3(256, 3), 256, 0, stream>>>(x, wT, bqkv, qb);
    k_attn<<<512, 512, 0, stream>>>(qb, kb, vb, mask, flag, x, g1, be1, x1);
    k_ffn<<<256, 256, 0, stream>>>(x1, wT + 49152, b1, wT + 65536, b2, g2, be2, out);
}

// Round 9
// 184.873 us; speedup vs baseline: 1.0683x; 1.0683x over previous
//
#include <hip/hip_runtime.h>
#include <cstdint>

#define NROWS 16384
#define ARRE ((size_t)NROWS * 128)

typedef short short8 __attribute__((ext_vector_type(8)));
typedef float f32x4  __attribute__((ext_vector_type(4)));
typedef float f32x16 __attribute__((ext_vector_type(16)));

static __device__ __forceinline__ unsigned short f2bf(float f) {
    union { float f; uint32_t u; } v; v.f = f;
    uint32_t r = v.u + 0x7fffu + ((v.u >> 16) & 1u);   // RNE
    return (unsigned short)(r >> 16);
}

static __device__ __forceinline__ uint32_t cvt_pk_bf16(float lo, float hi) {
    uint32_t r;
    asm("v_cvt_pk_bf16_f32 %0, %1, %2" : "=v"(r) : "v"(lo), "v"(hi));
    return r;
}

static __device__ __forceinline__ float v_exp2(float x) {   // 2^x, single instr
    float r;
    asm("v_exp_f32 %0, %1" : "=v"(r) : "v"(x));
    return r;
}

// ---------------------------------------------------------------- weights -> bf16 transposed (+ mask detect)
__global__ void k_castw(const float* __restrict__ wqkv, const float* __restrict__ w1,
                        const float* __restrict__ w2, unsigned short* __restrict__ wT,
                        const uint32_t* __restrict__ mask, int* __restrict__ flag)
{
    if (blockIdx.x == 320) {
        if (threadIdx.x == 0) {
            int f = 0;
            for (int i = 0; i < 256; ++i) f |= (mask[i] > 1u) ? 1 : 0;
            *flag = f;   // 1 => byte bool mask, 0 => int32 mask
        }
        return;
    }
    const int e = blockIdx.x * 256 + threadIdx.x;
    if (e < 49152) {
        const int n = e >> 7, k = e & 127;
        wT[e] = f2bf(wqkv[k * 384 + n]);
    } else if (e < 65536) {
        const int i = e - 49152, n = i >> 7, k = i & 127;
        wT[e] = f2bf(w1[k * 128 + n]);
    } else if (e < 81920) {
        const int i = e - 65536, n = i >> 7, k = i & 127;
        wT[e] = f2bf(w2[k * 128 + n]);
    }
}

// ---------------------------------------------------------------- MFMA QKV GEMM (unchanged from round 8)
template<int NF, int MODE>
__global__ __launch_bounds__(256, 2) void k_mm(const float* __restrict__ Xf,
        const unsigned short* __restrict__ Wt, const float* __restrict__ bias,
        unsigned short* __restrict__ out)
{
    __shared__ char smem[16384 + NF * 4096];
    char* const sX = smem;
    char* const sW = smem + 16384;
    const int t = threadIdx.x;
    const int w = t >> 6, l = t & 63;
    const int l4 = l >> 4, l15 = l & 15;
    const int r0 = blockIdx.x * 64;
    const int c0 = blockIdx.y * (NF * 16);

    #pragma unroll
    for (int i = 0; i < 4; ++i) {
        const int c = t + 256 * i;
        const int row = c >> 4, slot = c & 15;
        const float4* src = (const float4*)(Xf + (size_t)(r0 + row) * 128 + slot * 8);
        float4 f0 = src[0], f1 = src[1];
        uint4 v;
        v.x = cvt_pk_bf16(f0.x, f0.y);
        v.y = cvt_pk_bf16(f0.z, f0.w);
        v.z = cvt_pk_bf16(f1.x, f1.y);
        v.w = cvt_pk_bf16(f1.z, f1.w);
        *(uint4*)(sX + row * 256 + ((slot ^ (row & 15)) << 4)) = v;
    }
    #pragma unroll
    for (int i = 0; i < NF; ++i) {
        const int c = t + 256 * i;
        const int col = c >> 4, slot = c & 15;
        uint4 v = *(const uint4*)(Wt + (size_t)(c0 + col) * 128 + slot * 8);
        *(uint4*)(sW + col * 256 + ((slot ^ (col & 15)) << 4)) = v;
    }
    __syncthreads();

    short8 aF[4];
    #pragma unroll
    for (int kk = 0; kk < 4; ++kk)
        aF[kk] = *(const short8*)(sX + (w * 16 + l15) * 256 + (((kk * 4 + l4) ^ l15) << 4));

    f32x4 acc[NF];
    #pragma unroll
    for (int nf = 0; nf < NF; ++nf) acc[nf] = f32x4{0.f, 0.f, 0.f, 0.f};
    #pragma unroll
    for (int nf = 0; nf < NF; ++nf) {
        #pragma unroll
        for (int kk = 0; kk < 4; ++kk) {
            short8 bF = *(const short8*)(sW + (nf * 16 + l15) * 256 + (((kk * 4 + l4) ^ l15) << 4));
            acc[nf] = __builtin_amdgcn_mfma_f32_16x16x32_bf16(bF, aF[kk], acc[nf], 0, 0, 0);
        }
    }

    // Q scale folds hd^-0.5 * log2(e) (exp2-domain softmax)
    const float scl = (MODE == 0 && blockIdx.y == 0) ? 0.36067376022224085f : 1.0f;
    const int row = r0 + w * 16 + l15;
    #pragma unroll
    for (int nf = 0; nf < NF; ++nf) {
        const int cb = nf * 16 + l4 * 4;
        float4 bv = *(const float4*)(bias + c0 + cb);
        float v0 = acc[nf][0] + bv.x, v1 = acc[nf][1] + bv.y;
        float v2 = acc[nf][2] + bv.z, v3 = acc[nf][3] + bv.w;
        if (MODE == 1) {
            v0 = fmaxf(v0, 0.f); v1 = fmaxf(v1, 0.f);
            v2 = fmaxf(v2, 0.f); v3 = fmaxf(v3, 0.f);
        }
        v0 *= scl; v1 *= scl; v2 *= scl; v3 *= scl;
        uint2 pk;
        pk.x = cvt_pk_bf16(v0, v1);
        pk.y = cvt_pk_bf16(v2, v3);
        size_t o;
        if (MODE == 0) o = (size_t)blockIdx.y * ARRE + (size_t)row * 128 + cb;
        else           o = (size_t)row * 128 + c0 + cb;
        *(uint2*)(out + o) = pk;
    }
}

// ---------------------------------------------------------------- fused FFN (unchanged from round 8)
__global__ __launch_bounds__(256, 2) void k_ffn(const float* __restrict__ x1,
        const unsigned short* __restrict__ w1t, const float* __restrict__ b1,
        const unsigned short* __restrict__ w2t, const float* __restrict__ b2,
        const float* __restrict__ g2, const float* __restrict__ be2,
        float* __restrict__ out)
{
    __shared__ char smem[49152];
    char* const sX = smem;
    char* const sW = smem + 16384;
    const int t = threadIdx.x;
    const int w = t >> 6, l = t & 63;
    const int l4 = l >> 4, l15 = l & 15;
    const int r0 = blockIdx.x * 64;

    #pragma unroll
    for (int i = 0; i < 4; ++i) {
        const int c = t + 256 * i;
        const int row = c >> 4, slot = c & 15;
        const float4* src = (const float4*)(x1 + (size_t)(r0 + row) * 128 + slot * 8);
        float4 f0 = src[0], f1 = src[1];
        uint4 v;
        v.x = cvt_pk_bf16(f0.x, f0.y);
        v.y = cvt_pk_bf16(f0.z, f0.w);
        v.z = cvt_pk_bf16(f1.x, f1.y);
        v.w = cvt_pk_bf16(f1.z, f1.w);
        *(uint4*)(sX + row * 256 + ((slot ^ (row & 15)) << 4)) = v;
    }
    #pragma unroll
    for (int i = 0; i < 8; ++i) {
        const int c = t + 256 * i;
        const int col = c >> 4, slot = c & 15;
        uint4 v = *(const uint4*)(w1t + (size_t)col * 128 + slot * 8);
        *(uint4*)(sW + col * 256 + ((slot ^ (col & 15)) << 4)) = v;
    }
    __syncthreads();

    short8 aF[4];
    #pragma unroll
    for (int kk = 0; kk < 4; ++kk)
        aF[kk] = *(const short8*)(sX + (w * 16 + l15) * 256 + (((kk * 4 + l4) ^ l15) << 4));

    f32x4 acc[8];
    #pragma unroll
    for (int nf = 0; nf < 8; ++nf) acc[nf] = f32x4{0.f, 0.f, 0.f, 0.f};
    #pragma unroll
    for (int nf = 0; nf < 8; ++nf) {
        #pragma unroll
        for (int kk = 0; kk < 4; ++kk) {
            short8 bF = *(const short8*)(sW + (nf * 16 + l15) * 256 + (((kk * 4 + l4) ^ l15) << 4));
            acc[nf] = __builtin_amdgcn_mfma_f32_16x16x32_bf16(bF, aF[kk], acc[nf], 0, 0, 0);
        }
    }
    __syncthreads();

    {
        const int hrow = w * 16 + l15;
        #pragma unroll
        for (int nf = 0; nf < 8; ++nf) {
            const int cb = nf * 16 + l4 * 4;
            float4 bv = *(const float4*)(b1 + cb);
            float v0 = fmaxf(acc[nf][0] + bv.x, 0.f);
            float v1 = fmaxf(acc[nf][1] + bv.y, 0.f);
            float v2 = fmaxf(acc[nf][2] + bv.z, 0.f);
            float v3 = fmaxf(acc[nf][3] + bv.w, 0.f);
            uint2 pk;
            pk.x = cvt_pk_bf16(v0, v1);
            pk.y = cvt_pk_bf16(v2, v3);
            const int slot = (2 * nf) + (l4 >> 1);
            const int off  = (l4 & 1) * 8;
            *(uint2*)(sX + hrow * 256 + ((slot ^ (hrow & 15)) << 4) + off) = pk;
        }
    }
    #pragma unroll
    for (int i = 0; i < 8; ++i) {
        const int c = t + 256 * i;
        const int col = c >> 4, slot = c & 15;
        uint4 v = *(const uint4*)(w2t + (size_t)col * 128 + slot * 8);
        *(uint4*)(sW + col * 256 + ((slot ^ (col & 15)) << 4)) = v;
    }
    __syncthreads();

    short8 aG[4];
    #pragma unroll
    for (int kk = 0; kk < 4; ++kk)
        aG[kk] = *(const short8*)(sX + (w * 16 + l15) * 256 + (((kk * 4 + l4) ^ l15) << 4));

    f32x4 acc2[8];
    #pragma unroll
    for (int nf = 0; nf < 8; ++nf) acc2[nf] = f32x4{0.f, 0.f, 0.f, 0.f};
    #pragma unroll
    for (int nf = 0; nf < 8; ++nf) {
        #pragma unroll
        for (int kk = 0; kk < 4; ++kk) {
            short8 bF = *(const short8*)(sW + (nf * 16 + l15) * 256 + (((kk * 4 + l4) ^ l15) << 4));
            acc2[nf] = __builtin_amdgcn_mfma_f32_16x16x32_bf16(bF, aG[kk], acc2[nf], 0, 0, 0);
        }
    }

    const int row = r0 + w * 16 + l15;
    float y[8][4];
    float s = 0.f;
    #pragma unroll
    for (int nf = 0; nf < 8; ++nf) {
        const int cb = nf * 16 + l4 * 4;
        float4 bv = *(const float4*)(b2 + cb);
        float4 xv = *(const float4*)(x1 + (size_t)row * 128 + cb);
        y[nf][0] = acc2[nf][0] + bv.x + xv.x;
        y[nf][1] = acc2[nf][1] + bv.y + xv.y;
        y[nf][2] = acc2[nf][2] + bv.z + xv.z;
        y[nf][3] = acc2[nf][3] + bv.w + xv.w;
        s += y[nf][0] + y[nf][1] + y[nf][2] + y[nf][3];
    }
    s += __shfl_xor(s, 16); s += __shfl_xor(s, 32);
    const float mu = s * (1.f / 128.f);
    float vv = 0.f;
    #pragma unroll
    for (int nf = 0; nf < 8; ++nf) {
        #pragma unroll
        for (int reg = 0; reg < 4; ++reg) { float d = y[nf][reg] - mu; vv += d * d; }
    }
    vv += __shfl_xor(vv, 16); vv += __shfl_xor(vv, 32);
    const float rs = rsqrtf(vv * (1.f / 128.f) + 1e-5f);
    #pragma unroll
    for (int nf = 0; nf < 8; ++nf) {
        const int cb = nf * 16 + l4 * 4;
        float4 gv = *(const float4*)(g2 + cb);
        float4 ev = *(const float4*)(be2 + cb);
        float4 o;
        o.x = (y[nf][0] - mu) * rs * gv.x + ev.x;
        o.y = (y[nf][1] - mu) * rs * gv.y + ev.y;
        o.z = (y[nf][2] - mu) * rs * gv.z + ev.z;
        o.w = (y[nf][3] - mu) * rs * gv.w + ev.w;
        *(float4*)(out + (size_t)row * 128 + cb) = o;
    }
}

// ---------------------------------------------------------------- MFMA flash attention + fused LN1
// 512 thr = 8 waves (wave = head). Per tile: barrier -> write LDS from regs ->
// barrier -> prefetch next tile (T14) -> compute. PV = mfma32x32x16(A=V^T LDS,
// B=P in registers via cvt_pk + shfl_xor half-swap). acc cols = own q -> all
// softmax state lane-local. LDS 18688B: sK[0,8192) sVT[8192,18560) sM[18560,18688).
__global__ __launch_bounds__(512, 4) void k_attn(
        const unsigned short* __restrict__ qb,
        const unsigned short* __restrict__ kb,
        const unsigned short* __restrict__ vbp,
        const void* __restrict__ maskp, const int* __restrict__ flag,
        const float* __restrict__ x, const float* __restrict__ g1,
        const float* __restrict__ be1, float* __restrict__ x1)
{
    __shared__ alignas(16) char smem[18688];
    char*          const sK  = smem;
    char*          const sVT = smem + 8192;
    unsigned char* const sM  = (unsigned char*)(smem + 18560);

    const int t  = threadIdx.x;
    const int w  = t >> 6;        // head
    const int l  = t & 63;
    const int bid = blockIdx.x;
    const int b  = ((bid & 7) << 1) | (bid >> 8);          // XCD-local batches
    const int q0 = ((bid >> 3) & 31) * 32;
    const int q  = l & 31;
    const int hi = l >> 5;
    const int bytemask = *flag;

    // Q fragment (B of QK^T): lane holds Q[q][hd w*16 + hi*8 ..+7]
    const short8 qf = *(const short8*)(qb + (size_t)(b * 1024 + q0 + q) * 128 + w * 16 + hi * 8);

    // ---- hoisted staging addresses ----
    const int srow = t >> 4, sslot = t & 15;               // key row, 16B slot
    const size_t gbase = (size_t)(b * 1024 + srow) * 128 + sslot * 8;
    char* const wK = sK + srow * 256 + ((sslot ^ (srow & 15)) << 4);
    const int vh = sslot >> 1, vs = sslot & 1;             // head, d-half
    char* const wV = sVT + vh * 1296 + ((2 * srow + 16 * vs) & 63);  // + (8*vs+j)*80
    const int mq = t >> 2, mg = t & 3;
    const size_t mbase = ((size_t)b << 20) + (size_t)(q0 + mq) * 1024 + mg * 8;

    // ---- hoisted compute addresses ----
    const char* const rK = sK + q * 256 + ((((w << 1) | hi) ^ (q & 15)) << 4);
    const int dd = l & 15, sp = dd >> 3;
    const char* const rV = sVT + w * 1296 + dd * 80;
    const int vo0 = (16 * hi + 16 * sp) & 63;              // keys hi*8..+7
    const int vo1 = (32 + 16 * hi + 16 * sp) & 63;         // keys 16+hi*8..+7

    // ---- prefetch tile 0 ----
    uint4 kv, vv, ma = {0,0,0,0}, mb = {0,0,0,0};
    kv = *(const uint4*)(kb + gbase);
    vv = *(const uint4*)(vbp + gbase);
    if (t < 128) {
        if (bytemask) {
            uint2 v = *(const uint2*)((const uint8_t*)maskp + mbase);
            ma.x = v.x; ma.y = v.y;
        } else {
            const uint4* p4 = (const uint4*)((const int*)maskp + mbase);
            ma = p4[0]; mb = p4[1];
        }
    }

    float m = -INFINITY, ls = 0.f;
    f32x16 acc = {};
    const f32x16 z16 = {};
    union U8 { uint4 u; short8 s; };

    for (int kt = 0; kt < 32; ++kt) {
        __syncthreads();
        // ---- write LDS from regs ----
        *(uint4*)wK = kv;
        {
            const uint32_t w0 = vv.x, w1 = vv.y, w2 = vv.z, w3 = vv.w;
            *(unsigned short*)(wV + (8 * vs + 0) * 80) = (unsigned short)(w0);
            *(unsigned short*)(wV + (8 * vs + 1) * 80) = (unsigned short)(w0 >> 16);
            *(unsigned short*)(wV + (8 * vs + 2) * 80) = (unsigned short)(w1);
            *(unsigned short*)(wV + (8 * vs + 3) * 80) = (unsigned short)(w1 >> 16);
            *(unsigned short*)(wV + (8 * vs + 4) * 80) = (unsigned short)(w2);
            *(unsigned short*)(wV + (8 * vs + 5) * 80) = (unsigned short)(w2 >> 16);
            *(unsigned short*)(wV + (8 * vs + 6) * 80) = (unsigned short)(w3);
            *(unsigned short*)(wV + (8 * vs + 7) * 80) = (unsigned short)(w3 >> 16);
        }
        if (t < 128) {
            unsigned int bits = 0;
            if (bytemask) {
                uint64_t v = (uint64_t)ma.x | ((uint64_t)ma.y << 32);
                #pragma unroll
                for (int j = 0; j < 8; ++j)
                    bits |= ((((v >> (8 * j)) & 0xffull) == 0ull) ? 1u : 0u) << j;
            } else {
                bits = (ma.x==0?1u:0u) | (ma.y==0?2u:0u) | (ma.z==0?4u:0u) | (ma.w==0?8u:0u)
                     | (mb.x==0?16u:0u) | (mb.y==0?32u:0u) | (mb.z==0?64u:0u) | (mb.w==0?128u:0u);
            }
            sM[mq * 4 + mg] = (unsigned char)bits;
        }
        __syncthreads();
        // ---- prefetch next tile (T14: loads fly under compute) ----
        {
            const int kn = (kt + 1) & 31;
            const size_t g = gbase + (size_t)kn * 4096;
            kv = *(const uint4*)(kb + g);
            vv = *(const uint4*)(vbp + g);
            if (t < 128) {
                const size_t mo = mbase + (size_t)kn * 32;
                if (bytemask) {
                    uint2 v = *(const uint2*)((const uint8_t*)maskp + mo);
                    ma.x = v.x; ma.y = v.y;
                } else {
                    const uint4* p4 = (const uint4*)((const int*)maskp + mo);
                    ma = p4[0]; mb = p4[1];
                }
            }
        }
        // ---- compute ----
        const uint32_t mks = (*(const uint32_t*)(sM + q * 4)) >> (4 * hi);
        const short8 kf = *(const short8*)rK;
        f32x16 sc = __builtin_amdgcn_mfma_f32_32x32x16_bf16(kf, qf, z16, 0, 0, 0);
        float sm = sc[0];
        #pragma unroll
        for (int r = 1; r < 16; ++r) sm = fmaxf(sm, sc[r]);
        sm = fmaxf(sm, __shfl_xor(sm, 32));
        if (__any(sm > m + 8.f)) {                 // defer-max (THR=8, log2 units)
            const float nm = fmaxf(m, sm);
            const float s = v_exp2(m - nm);
            m = nm; ls *= s;
            #pragma unroll
            for (int r = 0; r < 8; ++r) acc[r] *= s;   // only d-rows 0-15 (regs 0-7) matter
        }
        float p[16]; float lsum = 0.f;
        #pragma unroll
        for (int r = 0; r < 16; ++r) {
            const int c = (r & 3) + 8 * (r >> 2);      // key = c + 4*hi
            float pv = v_exp2(sc[r] - m);
            pv = ((mks >> c) & 1u) ? pv : 0.f;
            lsum += pv; p[r] = pv;
        }
        ls += lsum;
        // pack P -> bf16 pairs; keys per pack: A:(4hi+0,1)(4hi+2,3) B:(8+4hi..) C:(16+4hi..) D:(24+4hi..)
        const uint32_t cA0 = cvt_pk_bf16(p[0],  p[1]),  cA1 = cvt_pk_bf16(p[2],  p[3]);
        const uint32_t cB0 = cvt_pk_bf16(p[4],  p[5]),  cB1 = cvt_pk_bf16(p[6],  p[7]);
        const uint32_t cC0 = cvt_pk_bf16(p[8],  p[9]),  cC1 = cvt_pk_bf16(p[10], p[11]);
        const uint32_t cD0 = cvt_pk_bf16(p[12], p[13]), cD1 = cvt_pk_bf16(p[14], p[15]);
        const uint32_t xA0 = __shfl_xor(cA0, 32), xA1 = __shfl_xor(cA1, 32);
        const uint32_t xB0 = __shfl_xor(cB0, 32), xB1 = __shfl_xor(cB1, 32);
        const uint32_t xC0 = __shfl_xor(cC0, 32), xC1 = __shfl_xor(cC1, 32);
        const uint32_t xD0 = __shfl_xor(cD0, 32), xD1 = __shfl_xor(cD1, 32);
        // B fragment: lane needs keys (mi*16 + hi*8 .. +7) ascending
        U8 pb0, pb1;
        pb0.u = hi ? uint4{xB0, xB1, cB0, cB1} : uint4{cA0, cA1, xA0, xA1};
        pb1.u = hi ? uint4{xD0, xD1, cD0, cD1} : uint4{cC0, cC1, xC0, xC1};
        // A = V^T: lane row = d (dup for lanes 16-31 of each half), k = keys
        const short8 va0 = *(const short8*)(rV + vo0);
        const short8 va1 = *(const short8*)(rV + vo1);
        acc = __builtin_amdgcn_mfma_f32_32x32x16_bf16(va0, pb0.s, acc, 0, 0, 0);
        acc = __builtin_amdgcn_mfma_f32_32x32x16_bf16(va1, pb1.s, acc, 0, 0, 0);
    }

    __syncthreads();
    // ---- epilogue: ctx -> LDS fp32 [32][132]; D row=(reg&3)+8*(reg>>2)+4hi = d, col = q ----
    float* const sC = (float*)smem;
    {
        const float inv = 1.f / (ls + __shfl_xor(ls, 32));
        float* const row = sC + q * 132 + w * 16 + 4 * hi;
        row[0] = acc[0] * inv; row[1] = acc[1] * inv;
        row[2] = acc[2] * inv; row[3] = acc[3] * inv;
        row[8] = acc[4] * inv; row[9] = acc[5] * inv;
        row[10] = acc[6] * inv; row[11] = acc[7] * inv;
    }
    __syncthreads();

    // ---- fused LN1: x1 = LN(x + ctx); 16 lanes/row, 8 cols/lane ----
    {
        const int row = t >> 4;
        const int c0  = (t & 15) * 8;
        const size_t grow = (size_t)(b * 1024 + q0 + row);
        const float4* xp = (const float4*)(x + grow * 128 + c0);
        const float4* cp = (const float4*)(sC + row * 132 + c0);
        float y[8];
        float s = 0.f;
        #pragma unroll
        for (int j = 0; j < 2; ++j) {
            float4 xv = xp[j], cv = cp[j];
            y[4*j+0] = xv.x + cv.x; y[4*j+1] = xv.y + cv.y;
            y[4*j+2] = xv.z + cv.z; y[4*j+3] = xv.w + cv.w;
            s += y[4*j+0] + y[4*j+1] + y[4*j+2] + y[4*j+3];
        }
        s += __shfl_xor(s, 1); s += __shfl_xor(s, 2);
        s += __shfl_xor(s, 4); s += __shfl_xor(s, 8);
        const float mu = s * (1.f / 128.f);
        float vv2 = 0.f;
        #pragma unroll
        for (int e = 0; e < 8; ++e) { float d = y[e] - mu; vv2 += d * d; }
        vv2 += __shfl_xor(vv2, 1); vv2 += __shfl_xor(vv2, 2);
        vv2 += __shfl_xor(vv2, 4); vv2 += __shfl_xor(vv2, 8);
        const float rs = rsqrtf(vv2 * (1.f / 128.f) + 1e-5f);
        #pragma unroll
        for (int j = 0; j < 2; ++j) {
            float4 gv = *(const float4*)(g1 + c0 + 4 * j);
            float4 bv = *(const float4*)(be1 + c0 + 4 * j);
            float4 o;
            o.x = (y[4*j+0] - mu) * rs * gv.x + bv.x;
            o.y = (y[4*j+1] - mu) * rs * gv.y + bv.y;
            o.z = (y[4*j+2] - mu) * rs * gv.z + bv.z;
            o.w = (y[4*j+3] - mu) * rs * gv.w + bv.w;
            *(float4*)(x1 + grow * 128 + c0 + 4 * j) = o;
        }
    }
}

// ---------------------------------------------------------------- launch
extern "C" void kernel_launch(void* const* d_in, const int* in_sizes, int n_in,
                              void* d_out, int out_size, void* d_ws, size_t ws_size,
                              hipStream_t stream)
{
    const float* x    = (const float*)d_in[0];
    const void*  mask = d_in[1];
    const float* wqkv = (const float*)d_in[2];
    const float* bqkv = (const float*)d_in[3];
    const float* w1   = (const float*)d_in[4];
    const float* b1   = (const float*)d_in[5];
    const float* w2   = (const float*)d_in[6];
    const float* b2   = (const float*)d_in[7];
    const float* g1   = (const float*)d_in[8];
    const float* be1  = (const float*)d_in[9];
    const float* g2   = (const float*)d_in[10];
    const float* be2  = (const float*)d_in[11];
    float* out = (float*)d_out;

    char* base = (char*)d_ws;
    int* flag = (int*)base;
    unsigned short* qb  = (unsigned short*)(base + 256);                   // 4MB
    unsigned short* kb  = qb + ARRE;                                       // 4MB
    unsigned short* vb  = kb + ARRE;                                       // 4MB
    float* x1           = (float*)(base + 256 + (size_t)12 * 1024 * 1024); // 8MB
    unsigned short* wT  = (unsigned short*)(base + 256 + (size_t)20 * 1024 * 1024); // 160KB

    k_castw<<<321, 256, 0, stream>>>(wqkv, w1, w2, wT, (const uint32_t*)mask, flag);
    k_mm<8, 0><<<dim3(256, 3), 256, 0, stream>>>(x, wT, bqkv, qb);
    k_attn<<<512, 512, 0, stream>>>(qb, kb, vb, mask, flag, x, g1, be1, x1);
    k_ffn<<<256, 256, 0, stream>>>(x1, wT + 49152, b1, wT + 65536, b2, g2, be2, out);
}